// Round 16
// baseline (1196.226 us; speedup 1.0000x reference)
//
#include <hip/hip_runtime.h>
#include <math.h>

// ---------------- problem constants ----------------
#define NB   16

// d_out float offsets
#define O_P1 0
#define O_F1 (16*3*1024)            // 49152
#define O_P2 (O_F1 + 16*128*1024)   // 2146304
#define O_F2 (O_P2 + 16*3*256)      // 2158592

// workspace byte offsets
#define WS_GIDX1 0
#define WS_GIDX2 (WS_GIDX1 + 16*1024*32*4)
#define WS_W1H   (WS_GIDX2 + 16*256*64*4)     // fp16 [128][160]  (mlp2 L1)
#define WS_W2H   (WS_W1H  + 128*160*2)        // fp16 [128][128]
#define WS_W3H   (WS_W2H  + 128*128*2)        // fp16 [256][128]
#define WS_W1MH  (WS_W3H  + 256*128*2)        // fp16 [64][32]    (mlp1 L1, K pad 32)
#define WS_W2MH  (WS_W1MH + 64*32*2)          // fp16 [64][64]
#define WS_W3MH  (WS_W2MH + 64*64*2)          // fp16 [128][64]
#define WS_PTS4  (WS_W3MH + 128*64*2)         // float4[16][4096] (x,y,z,|p|^2)
#define WS_P14   (WS_PTS4 + 16*4096*16)       // float4[16][1024] packed p1

#define DEVINL __device__ __forceinline__
typedef unsigned long long u64;
typedef _Float16 f16x8 __attribute__((ext_vector_type(8)));
typedef float f32x4 __attribute__((ext_vector_type(4)));

// order-preserving float -> uint mapping (monotone increasing)
DEVINL unsigned fkey(float f) {
    unsigned u = __float_as_uint(f);
    return (u & 0x80000000u) ? ~u : (u | 0x80000000u);
}

DEVINL u64 shflx64(u64 v, int m) {
    unsigned lo = __shfl_xor((unsigned)v, m);
    unsigned hi = __shfl_xor((unsigned)(v >> 32), m);
    return ((u64)hi << 32) | lo;
}

// inclusive add-scan within wave64 (bcast15 -> rows 1&3, bcast31 -> rows 2&3)
template<int CTRL, int RMASK>
DEVINL unsigned dpp_addstep(unsigned v) {
    unsigned t = (unsigned)__builtin_amdgcn_update_dpp(0, (int)v, CTRL, RMASK, 0xF, true);
    return v + t;
}
DEVINL unsigned wave_scan_add(unsigned v) {
    v = dpp_addstep<0x111, 0xF>(v);
    v = dpp_addstep<0x112, 0xF>(v);
    v = dpp_addstep<0x114, 0xF>(v);
    v = dpp_addstep<0x118, 0xF>(v);
    v = dpp_addstep<0x142, 0xA>(v);
    v = dpp_addstep<0x143, 0xC>(v);
    return v;
}

// XOR-swizzled half-index helpers (16B chunks) — SAME function for write & read.
DEVINL int swz32(int n, int h) {   // row stride 32 halves (64B), 4 chunks
    return n*32 + (((h >> 3) ^ (n & 3)) << 3) + (h & 7);
}
DEVINL int swz64(int n, int h) {   // row stride 64 halves (128B), 8 chunks
    return n*64 + (((h >> 3) ^ (n & 7)) << 3) + (h & 7);
}

// ---------------- shared-memory layouts ----------------
template<int N, int NP> struct __align__(16) FpsS {      // 4-wave FPS
    float4 spts[N];
    int sel[NP];
    u64 rbuf[2][4];
};
struct __align__(16) KnnS {                              // keyless: ~16.4KB
    unsigned hist[2048];
    unsigned ckey[1024];
    int      cidx[1024];
    unsigned wpart[4];
    unsigned sbin, sKb, scnt, cntL;
};
struct __align__(16) Mlp1MS {                            // ~53.3KB
    _Float16 xT [256*32];
    _Float16 h1T[256*64];
    float sout[128*8];
    int   sgi[256];
    float sq[24];
};

// ---------------- weight prep: all fp16, gamma-folded ----------------
DEVINL void prep_impl(int e0,
    const float* __restrict__ w10, const float* __restrict__ g10,
    const float* __restrict__ w11, const float* __restrict__ g11,
    const float* __restrict__ w12, const float* __restrict__ g12,
    const float* __restrict__ w20, const float* __restrict__ g20,
    const float* __restrict__ w21, const float* __restrict__ g21,
    const float* __restrict__ w22, const float* __restrict__ g22,
    _Float16* __restrict__ W1h, _Float16* __restrict__ W2h, _Float16* __restrict__ W3h,
    _Float16* __restrict__ W1mh, _Float16* __restrict__ W2mh, _Float16* __restrict__ W3mh)
{
    if (e0 < 20480){ int o = e0/160, i = e0%160;
                     float v = (i < 131) ? w20[o*131 + i]*g20[o] : 0.f;
                     W1h[e0] = (_Float16)v; return; }
    e0 -= 20480;
    if (e0 < 16384){ W2h[e0] = (_Float16)(w21[e0]*g21[e0/128]); return; }
    e0 -= 16384;
    if (e0 < 32768){ W3h[e0] = (_Float16)(w22[e0]*g22[e0/128]); return; }
    e0 -= 32768;
    if (e0 < 2048) { int o = e0>>5, i = e0&31;
                     float v = (i < 6) ? w10[o*6 + i]*g10[o] : 0.f;
                     W1mh[e0] = (_Float16)v; return; }
    e0 -= 2048;
    if (e0 < 4096) { W2mh[e0] = (_Float16)(w11[e0]*g11[e0>>6]); return; }
    e0 -= 4096;
    if (e0 < 8192) { W3mh[e0] = (_Float16)(w12[e0]*g12[e0>>6]); return; }
}

// ---------------- FPS 4-wave (R8 structure; exact jnp semantics) ----------------
template<int N, int NP>
DEVINL void fps_impl(FpsS<N, NP>& sm, const float* __restrict__ pts,
                     float* __restrict__ prop, int b, float4* pack_out)
{
    constexpr int NT = 256;
    constexpr int PT = N / NT;
    int tid = threadIdx.x;
    const float* p = pts + (size_t)b * 3 * N;
    for (int n = tid; n < N; n += NT) {
        float x = p[n], y = p[N+n], z = p[2*N+n];
        sm.spts[n] = make_float4(x, y, z, 0.f);
        if (pack_out) {
            float s = __fadd_rn(__fadd_rn(__fmul_rn(x,x), __fmul_rn(y,y)), __fmul_rn(z,z));
            pack_out[(size_t)b*N + n] = make_float4(x, y, z, s);
        }
    }
    __syncthreads();

    float lx[PT], ly[PT], lz[PT], ld[PT];
    int base = tid * PT;
#pragma unroll
    for (int j = 0; j < PT; ++j) {
        float4 q = sm.spts[base+j];
        lx[j] = q.x; ly[j] = q.y; lz[j] = q.z;
        ld[j] = __builtin_inff();
    }
    if (tid == 0) sm.sel[0] = 0;
    float4 qp = sm.spts[0];
    for (int s = 1; s < NP; ++s) {
        float qx = qp.x, qy = qp.y, qz = qp.z;
        float bd = -1.0f; int bi = 0x7FFFFFFF;
#pragma unroll
        for (int j = 0; j < PT; ++j) {
            float dx = __fsub_rn(lx[j], qx);
            float dy = __fsub_rn(ly[j], qy);
            float dz = __fsub_rn(lz[j], qz);
            float dd = __fadd_rn(__fadd_rn(__fmul_rn(dx,dx), __fmul_rn(dy,dy)), __fmul_rn(dz,dz));
            float v = fminf(ld[j], dd);
            ld[j] = v;
            if (v > bd) { bd = v; bi = base + j; }   // ascending j -> lowest idx on tie
        }
        u64 pk = ((u64)__float_as_uint(bd) << 32) | (unsigned)(~bi);
#pragma unroll
        for (int mk = 1; mk < 64; mk <<= 1) {
            u64 o = shflx64(pk, mk);
            if (o > pk) pk = o;
        }
        if ((tid & 63) == 0) sm.rbuf[s & 1][tid >> 6] = pk;
        __syncthreads();
        u64 g = sm.rbuf[s & 1][0];
#pragma unroll
        for (int w = 1; w < 4; ++w) { u64 o = sm.rbuf[s & 1][w]; if (o > g) g = o; }
        int last = (int)(~(unsigned)g);
        qp = sm.spts[last];
        if (tid == 0) sm.sel[s] = last;
    }
    __syncthreads();
    for (int m = tid; m < NP; m += NT) {
        float4 q = sm.spts[sm.sel[m]];
        prop[(size_t)b*3*NP + m]        = q.x;
        prop[(size_t)b*3*NP + NP + m]   = q.y;
        prop[(size_t)b*3*NP + 2*NP + m] = q.z;
    }
}

// ---------------- KNN keyless (packed points): 11-bit histogram select ----------
template<int N, int K, int M>
DEVINL void knn_impl(KnnS& sm, const float4* __restrict__ pts4,
                     const float* __restrict__ qry, int* __restrict__ gidx, int bm)
{
    int tid = threadIdx.x, lane = tid & 63, wid = tid >> 6;
    int b = bm / M, m = bm % M;
    const float4* p4 = pts4 + (size_t)b * N;
    float qx = qry[(size_t)b*3*M + m];
    float qy = qry[(size_t)b*3*M + M + m];
    float qz = qry[(size_t)b*3*M + 2*M + m];
    float sqq = __fadd_rn(__fadd_rn(__fmul_rn(qx,qx), __fmul_rn(qy,qy)), __fmul_rn(qz,qz));

    for (int e = tid; e < 2048; e += 256) sm.hist[e] = 0;
    if (tid == 0) { sm.scnt = 0; sm.cntL = 0; sm.sbin = 2047u; sm.sKb = 0; }
    __syncthreads();
    for (int n = tid; n < N; n += 256) {
        float4 pp = p4[n];
        float dot = __fadd_rn(__fadd_rn(__fmul_rn(qx,pp.x), __fmul_rn(qy,pp.y)), __fmul_rn(qz,pp.z));
        float d = __fadd_rn(__fsub_rn(sqq, __fmul_rn(2.0f, dot)), pp.w);
        atomicAdd(&sm.hist[fkey(d) >> 21], 1u);
    }
    __syncthreads();
    unsigned hloc[8], s8 = 0;
#pragma unroll
    for (int j = 0; j < 8; ++j) { hloc[j] = sm.hist[tid*8 + j]; s8 += hloc[j]; }
    unsigned sc = wave_scan_add(s8);
    if (lane == 63) sm.wpart[wid] = sc;
    __syncthreads();
    unsigned woff = 0;
    for (int w = 0; w < wid; ++w) woff += sm.wpart[w];
    unsigned cumEnd = sc + woff;
    unsigned cbase = cumEnd - s8;
    if ((unsigned)K > cbase && (unsigned)K <= cumEnd) {
        unsigned run = cbase;
#pragma unroll
        for (int j = 0; j < 8; ++j) {
            if ((unsigned)K > run && (unsigned)K <= run + hloc[j]) { sm.sbin = (unsigned)(tid*8 + j); sm.sKb = run; }
            run += hloc[j];
        }
    }
    __syncthreads();
    unsigned bin1 = sm.sbin;
    unsigned Kb   = sm.sKb;
    int* gout = gidx + ((size_t)b * M + m) * K;
    for (int n = tid; n < N; n += 256) {
        float4 pp = p4[n];
        float dot = __fadd_rn(__fadd_rn(__fmul_rn(qx,pp.x), __fmul_rn(qy,pp.y)), __fmul_rn(qz,pp.z));
        float d = __fadd_rn(__fsub_rn(sqq, __fmul_rn(2.0f, dot)), pp.w);
        unsigned k = fkey(d), pfx = k >> 21;
        if (pfx < bin1) {
            unsigned pos = atomicAdd(&sm.cntL, 1u);
            if (pos < (unsigned)K) gout[pos] = n;
        } else if (pfx == bin1) {
            unsigned pos = atomicAdd(&sm.scnt, 1u);
            if (pos < 1024u) { sm.ckey[pos] = k; sm.cidx[pos] = n; }
        }
    }
    __syncthreads();
    int cnt = (int)sm.scnt; if (cnt > 1024) cnt = 1024;
    int need = K - (int)Kb;
    if (tid < 64) {
        for (int c = lane; c < cnt; c += 64) {
            unsigned mk = sm.ckey[c]; int mi = sm.cidx[c];
            int rank = 0;
            for (int l = 0; l < cnt; ++l) {
                unsigned ok = sm.ckey[l];
                rank += (ok < mk || (ok == mk && sm.cidx[l] < mi)) ? 1 : 0;
            }
            if (rank < need && (int)Kb + rank < K) gout[Kb + rank] = mi;
        }
    }
}

// ---------------- mlp1 via fp16 MFMA (device impl) ----------------
// One block per 8 positions; wave-local h rows -> no barriers in GEMM chain.
DEVINL void mlp1_mfma_impl(Mlp1MS& sm,
    const float4* __restrict__ pts4,
    const float* __restrict__ q,
    const int*   __restrict__ gidx,
    const _Float16* __restrict__ W1mh, const _Float16* __restrict__ W2mh,
    const _Float16* __restrict__ W3mh,
    const float* __restrict__ b1, const float* __restrict__ b2, const float* __restrict__ b3,
    float* __restrict__ out, int blk)
{
    int tid = threadIdx.x;
    int pid0 = blk * 8;
    int b = pid0 >> 10, m0 = pid0 & 1023;

    sm.sgi[tid] = gidx[((size_t)b*1024 + m0)*32 + tid];
    if (tid < 24) {
        int c = tid >> 3, j = tid & 7;
        sm.sq[tid] = q[((size_t)b*3 + c)*1024 + m0 + j];
    }
    __syncthreads();

    union Pk4 { _Float16 h[4]; u64 u; };
    {
        int n = tid, pos = n >> 5;
        float4 pp = pts4[(size_t)b*4096 + sm.sgi[n]];
        float v[8];
        v[0] = pp.x - sm.sq[pos]; v[1] = pp.y - sm.sq[8+pos]; v[2] = pp.z - sm.sq[16+pos];
        v[3] = pp.x; v[4] = pp.y; v[5] = pp.z; v[6] = 0.f; v[7] = 0.f;
#pragma unroll
        for (int qi = 0; qi < 8; ++qi) {
            Pk4 pk;
            if (qi < 2) {
#pragma unroll
                for (int j = 0; j < 4; ++j) pk.h[j] = (_Float16)v[qi*4 + j];
            } else pk.u = 0;
            *(u64*)&sm.xT[swz32(n, qi*4)] = pk.u;
        }
    }
    __syncthreads();

    int wv = tid >> 6, l = tid & 63;
    int lr = l & 15, lk = l >> 4;

    // GEMM1: H1[64][256] = W1[64][32] * X[32][256]
    f32x4 acc[4][4];
#pragma unroll
    for (int mi = 0; mi < 4; ++mi)
#pragma unroll
        for (int nt = 0; nt < 4; ++nt) acc[mi][nt] = (f32x4){0.f,0.f,0.f,0.f};
    {
        int kk = lk*8;
        f16x8 bf[4];
#pragma unroll
        for (int nt = 0; nt < 4; ++nt)
            bf[nt] = *(const f16x8*)&sm.xT[swz32((4*wv + nt)*16 + lr, kk)];
#pragma unroll
        for (int mi = 0; mi < 4; ++mi) {
            f16x8 af = *(const f16x8*)&W1mh[(mi*16 + lr)*32 + kk];
#pragma unroll
            for (int nt = 0; nt < 4; ++nt)
                acc[mi][nt] = __builtin_amdgcn_mfma_f32_16x16x32_f16(af, bf[nt], acc[mi][nt], 0, 0, 0);
        }
    }
#pragma unroll
    for (int mi = 0; mi < 4; ++mi) {
        int ch0 = mi*16 + lk*4;
        float bb0 = b1[ch0], bb1 = b1[ch0+1], bb2 = b1[ch0+2], bb3 = b1[ch0+3];
#pragma unroll
        for (int nt = 0; nt < 4; ++nt) {
            int n = (4*wv + nt)*16 + lr;
            Pk4 pk;
            pk.h[0] = (_Float16)fmaxf(acc[mi][nt][0] + bb0, 0.f);
            pk.h[1] = (_Float16)fmaxf(acc[mi][nt][1] + bb1, 0.f);
            pk.h[2] = (_Float16)fmaxf(acc[mi][nt][2] + bb2, 0.f);
            pk.h[3] = (_Float16)fmaxf(acc[mi][nt][3] + bb3, 0.f);
            *(u64*)&sm.h1T[swz64(n, ch0)] = pk.u;
        }
    }

    // GEMM2: H2 = W2 * H1 (wave-local rows; in-place)
#pragma unroll
    for (int mi = 0; mi < 4; ++mi)
#pragma unroll
        for (int nt = 0; nt < 4; ++nt) acc[mi][nt] = (f32x4){0.f,0.f,0.f,0.f};
#pragma unroll
    for (int ks = 0; ks < 2; ++ks) {
        int kk = ks*32 + lk*8;
        f16x8 bf[4];
#pragma unroll
        for (int nt = 0; nt < 4; ++nt)
            bf[nt] = *(const f16x8*)&sm.h1T[swz64((4*wv + nt)*16 + lr, kk)];
#pragma unroll
        for (int mi = 0; mi < 4; ++mi) {
            f16x8 af = *(const f16x8*)&W2mh[(mi*16 + lr)*64 + kk];
#pragma unroll
            for (int nt = 0; nt < 4; ++nt)
                acc[mi][nt] = __builtin_amdgcn_mfma_f32_16x16x32_f16(af, bf[nt], acc[mi][nt], 0, 0, 0);
        }
    }
#pragma unroll
    for (int mi = 0; mi < 4; ++mi) {
        int ch0 = mi*16 + lk*4;
        float bb0 = b2[ch0], bb1 = b2[ch0+1], bb2 = b2[ch0+2], bb3 = b2[ch0+3];
#pragma unroll
        for (int nt = 0; nt < 4; ++nt) {
            int n = (4*wv + nt)*16 + lr;
            Pk4 pk;
            pk.h[0] = (_Float16)fmaxf(acc[mi][nt][0] + bb0, 0.f);
            pk.h[1] = (_Float16)fmaxf(acc[mi][nt][1] + bb1, 0.f);
            pk.h[2] = (_Float16)fmaxf(acc[mi][nt][2] + bb2, 0.f);
            pk.h[3] = (_Float16)fmaxf(acc[mi][nt][3] + bb3, 0.f);
            *(u64*)&sm.h1T[swz64(n, ch0)] = pk.u;
        }
    }

    // GEMM3: Y[128][256] = W3[128][64] * H2 + maxpool(32)
    f32x4 acc3[8][4];
#pragma unroll
    for (int mi = 0; mi < 8; ++mi)
#pragma unroll
        for (int nt = 0; nt < 4; ++nt) acc3[mi][nt] = (f32x4){0.f,0.f,0.f,0.f};
#pragma unroll
    for (int ks = 0; ks < 2; ++ks) {
        int kk = ks*32 + lk*8;
        f16x8 bf[4];
#pragma unroll
        for (int nt = 0; nt < 4; ++nt)
            bf[nt] = *(const f16x8*)&sm.h1T[swz64((4*wv + nt)*16 + lr, kk)];
#pragma unroll
        for (int mi = 0; mi < 8; ++mi) {
            f16x8 af = *(const f16x8*)&W3mh[(mi*16 + lr)*64 + kk];
#pragma unroll
            for (int nt = 0; nt < 4; ++nt)
                acc3[mi][nt] = __builtin_amdgcn_mfma_f32_16x16x32_f16(af, bf[nt], acc3[mi][nt], 0, 0, 0);
        }
    }
#pragma unroll
    for (int mi = 0; mi < 8; ++mi) {
        float va[4], vb[4];
#pragma unroll
        for (int r = 0; r < 4; ++r) {
            va[r] = fmaxf(acc3[mi][0][r], acc3[mi][1][r]);
            vb[r] = fmaxf(acc3[mi][2][r], acc3[mi][3][r]);
        }
#pragma unroll
        for (int mk = 1; mk < 16; mk <<= 1) {
#pragma unroll
            for (int r = 0; r < 4; ++r) {
                va[r] = fmaxf(va[r], __shfl_xor(va[r], mk));
                vb[r] = fmaxf(vb[r], __shfl_xor(vb[r], mk));
            }
        }
        if (lr == 0) {
            int ch0 = mi*16 + lk*4;
#pragma unroll
            for (int r = 0; r < 4; ++r) {
                float bias = b3[ch0 + r];
                sm.sout[(ch0 + r)*8 + 2*wv    ] = fmaxf(va[r] + bias, 0.f);
                sm.sout[(ch0 + r)*8 + 2*wv + 1] = fmaxf(vb[r] + bias, 0.f);
            }
        }
    }
    __syncthreads();
    for (int e = tid; e < 128*8; e += 256) {
        int cc = e >> 3, j = e & 7;
        out[((size_t)b*128 + cc)*1024 + m0 + j] = sm.sout[e];
    }
}

// ---------------- fused kernels ----------------
// K1: fps1 (0..15) || prep fp16 weights (16..343) || pack pts4 (344..407)
__global__ __launch_bounds__(256) void fused1(
    const float* __restrict__ pts, float* __restrict__ p1, float4* __restrict__ pts4,
    const float* w10, const float* g10, const float* w11, const float* g11,
    const float* w12, const float* g12, const float* w20, const float* g20,
    const float* w21, const float* g21, const float* w22, const float* g22,
    _Float16* W1h, _Float16* W2h, _Float16* W3h,
    _Float16* W1mh, _Float16* W2mh, _Float16* W3mh)
{
    __shared__ FpsS<4096, 1024> sm;
    if (blockIdx.x < 16) {
        fps_impl<4096, 1024>(sm, pts, p1, blockIdx.x, nullptr);
    } else if (blockIdx.x < 344) {
        prep_impl((blockIdx.x - 16) * 256 + threadIdx.x,
                  w10, g10, w11, g11, w12, g12, w20, g20, w21, g21, w22, g22,
                  W1h, W2h, W3h, W1mh, W2mh, W3mh);
    } else {
        int pblk = blockIdx.x - 344;   // 0..63, 1024 points each
#pragma unroll
        for (int i = 0; i < 4; ++i) {
            int idx = pblk * 1024 + i * 256 + threadIdx.x;
            int b = idx >> 12, n = idx & 4095;
            const float* p = pts + (size_t)b * 3 * 4096;
            float x = p[n], y = p[4096 + n], z = p[2*4096 + n];
            float s = __fadd_rn(__fadd_rn(__fmul_rn(x,x), __fmul_rn(y,y)), __fmul_rn(z,z));
            pts4[idx] = make_float4(x, y, z, s);
        }
    }
}

// K2: fps2 4-wave (0..15, packs p14) || knn1 (16..16399)
union SmemK2 { FpsS<1024, 256> fps; KnnS knn; };
__global__ __launch_bounds__(256) void fused2(
    const float4* __restrict__ pts4, const float* __restrict__ p1,
    float* __restrict__ p2, int* __restrict__ gidx1, float4* __restrict__ p14)
{
    __shared__ SmemK2 sm;
    if (blockIdx.x < 16) {
        fps_impl<1024, 256>(sm.fps, p1, p2, blockIdx.x, p14);
    } else {
        knn_impl<4096, 32, 1024>(sm.knn, pts4, p1, gidx1, blockIdx.x - 16);
    }
}

// K3: mlp1 MFMA (0..2047) || knn2 (2048..6143) — independent inputs, R12 pattern
union SmemK3 { Mlp1MS mlp; KnnS knn; };
__global__ __launch_bounds__(256) void fused3(
    const float4* __restrict__ pts4, const float* __restrict__ p1,
    const int* __restrict__ gidx1,
    const _Float16* __restrict__ W1mh, const _Float16* __restrict__ W2mh,
    const _Float16* __restrict__ W3mh,
    const float* __restrict__ b1, const float* __restrict__ b2, const float* __restrict__ b3,
    float* __restrict__ f1,
    const float4* __restrict__ p14, const float* __restrict__ p2, int* __restrict__ gidx2)
{
    __shared__ SmemK3 sm;
    if (blockIdx.x < 2048) {
        mlp1_mfma_impl(sm.mlp, pts4, p1, gidx1, W1mh, W2mh, W3mh, b1, b2, b3, f1, blockIdx.x);
    } else {
        knn_impl<1024, 64, 256>(sm.knn, p14, p2, gidx2, blockIdx.x - 2048);
    }
}

// ---------------- K4: mlp2 via fp16 MFMA (R14, verified) ----------------
__global__ __launch_bounds__(256) void mlp2_kernel(
    const float* __restrict__ p1,   // [B,3,1024]
    const float* __restrict__ f1,   // [B,128,1024]
    const float* __restrict__ q2,   // [B,3,256]
    const int*   __restrict__ gidx, // [B,256,64]
    const _Float16* __restrict__ W1h,  // [128][160]
    const _Float16* __restrict__ W2h,  // [128][128]
    const _Float16* __restrict__ W3h,  // [256][128]
    const float* __restrict__ b20, const float* __restrict__ b21, const float* __restrict__ b22,
    float* __restrict__ out)        // feats2 [B,256,256]
{
    __shared__ _Float16 xT[64*168];    // X^T (n-major, stride 168); later h2T (stride 136)
    __shared__ _Float16 h1T[64*136];
    __shared__ int   sgi[64];
    __shared__ float sq[3];

    int tid = threadIdx.x;
    int b = blockIdx.x >> 8, m = blockIdx.x & 255;
    if (tid < 64) sgi[tid] = gidx[((size_t)b*256 + m)*64 + tid];
    else if (tid < 67) sq[tid-64] = q2[((size_t)b*3 + (tid-64))*256 + m];
    __syncthreads();

    union Pk4 { _Float16 h[4]; u64 u; };
    for (int e = tid; e < 40*64; e += 256) {
        int qi = e >> 6, n = e & 63;
        int gi = sgi[n];
        Pk4 pk;
#pragma unroll
        for (int j = 0; j < 4; ++j) {
            int i = qi*4 + j;
            float v;
            if (i < 3)        v = p1[((size_t)b*3 + i)*1024 + gi] - sq[i];
            else if (i < 131) v = f1[((size_t)b*128 + (i-3))*1024 + gi];
            else              v = 0.f;
            pk.h[j] = (_Float16)v;
        }
        *(u64*)&xT[n*168 + qi*4] = pk.u;
    }
    __syncthreads();

    int wv = tid >> 6, l = tid & 63;
    int lr = l & 15, lk = l >> 4;

    // GEMM1: Y1[128][64] = W1[128][160] * X[160][64]
    f32x4 acc[2][4];
#pragma unroll
    for (int mi = 0; mi < 2; ++mi)
#pragma unroll
        for (int nt = 0; nt < 4; ++nt) acc[mi][nt] = (f32x4){0.f,0.f,0.f,0.f};
#pragma unroll
    for (int ks = 0; ks < 5; ++ks) {
        int kk = ks*32 + lk*8;
        f16x8 bf[4];
#pragma unroll
        for (int nt = 0; nt < 4; ++nt)
            bf[nt] = *(const f16x8*)&xT[(nt*16 + lr)*168 + kk];
#pragma unroll
        for (int mi = 0; mi < 2; ++mi) {
            f16x8 af = *(const f16x8*)&W1h[(size_t)((wv*2 + mi)*16 + lr)*160 + kk];
#pragma unroll
            for (int nt = 0; nt < 4; ++nt)
                acc[mi][nt] = __builtin_amdgcn_mfma_f32_16x16x32_f16(af, bf[nt], acc[mi][nt], 0, 0, 0);
        }
    }
#pragma unroll
    for (int mi = 0; mi < 2; ++mi) {
        int ch0 = (wv*2 + mi)*16 + lk*4;
        float bb0 = b20[ch0], bb1 = b20[ch0+1], bb2 = b20[ch0+2], bb3 = b20[ch0+3];
#pragma unroll
        for (int nt = 0; nt < 4; ++nt) {
            int n = nt*16 + lr;
            Pk4 pk;
            pk.h[0] = (_Float16)fmaxf(acc[mi][nt][0] + bb0, 0.f);
            pk.h[1] = (_Float16)fmaxf(acc[mi][nt][1] + bb1, 0.f);
            pk.h[2] = (_Float16)fmaxf(acc[mi][nt][2] + bb2, 0.f);
            pk.h[3] = (_Float16)fmaxf(acc[mi][nt][3] + bb3, 0.f);
            *(u64*)&h1T[n*136 + ch0] = pk.u;
        }
    }
    __syncthreads();

    // GEMM2: Y2 = W2 * H1; h2T into xT region
    _Float16* h2T = xT;
#pragma unroll
    for (int mi = 0; mi < 2; ++mi)
#pragma unroll
        for (int nt = 0; nt < 4; ++nt) acc[mi][nt] = (f32x4){0.f,0.f,0.f,0.f};
#pragma unroll
    for (int ks = 0; ks < 4; ++ks) {
        int kk = ks*32 + lk*8;
        f16x8 bf[4];
#pragma unroll
        for (int nt = 0; nt < 4; ++nt)
            bf[nt] = *(const f16x8*)&h1T[(nt*16 + lr)*136 + kk];
#pragma unroll
        for (int mi = 0; mi < 2; ++mi) {
            f16x8 af = *(const f16x8*)&W2h[(size_t)((wv*2 + mi)*16 + lr)*128 + kk];
#pragma unroll
            for (int nt = 0; nt < 4; ++nt)
                acc[mi][nt] = __builtin_amdgcn_mfma_f32_16x16x32_f16(af, bf[nt], acc[mi][nt], 0, 0, 0);
        }
    }
    __syncthreads();
#pragma unroll
    for (int mi = 0; mi < 2; ++mi) {
        int ch0 = (wv*2 + mi)*16 + lk*4;
        float bb0 = b21[ch0], bb1 = b21[ch0+1], bb2 = b21[ch0+2], bb3 = b21[ch0+3];
#pragma unroll
        for (int nt = 0; nt < 4; ++nt) {
            int n = nt*16 + lr;
            Pk4 pk;
            pk.h[0] = (_Float16)fmaxf(acc[mi][nt][0] + bb0, 0.f);
            pk.h[1] = (_Float16)fmaxf(acc[mi][nt][1] + bb1, 0.f);
            pk.h[2] = (_Float16)fmaxf(acc[mi][nt][2] + bb2, 0.f);
            pk.h[3] = (_Float16)fmaxf(acc[mi][nt][3] + bb3, 0.f);
            *(u64*)&h2T[n*136 + ch0] = pk.u;
        }
    }
    __syncthreads();

    // GEMM3: Y3[256][64] = W3 * H2, maxpool over n
    f32x4 acc3[4][4];
#pragma unroll
    for (int mi = 0; mi < 4; ++mi)
#pragma unroll
        for (int nt = 0; nt < 4; ++nt) acc3[mi][nt] = (f32x4){0.f,0.f,0.f,0.f};
#pragma unroll
    for (int ks = 0; ks < 4; ++ks) {
        int kk = ks*32 + lk*8;
        f16x8 bf[4];
#pragma unroll
        for (int nt = 0; nt < 4; ++nt)
            bf[nt] = *(const f16x8*)&h2T[(nt*16 + lr)*136 + kk];
#pragma unroll
        for (int mi = 0; mi < 4; ++mi) {
            f16x8 af = *(const f16x8*)&W3h[(size_t)((wv*4 + mi)*16 + lr)*128 + kk];
#pragma unroll
            for (int nt = 0; nt < 4; ++nt)
                acc3[mi][nt] = __builtin_amdgcn_mfma_f32_16x16x32_f16(af, bf[nt], acc3[mi][nt], 0, 0, 0);
        }
    }
#pragma unroll
    for (int mi = 0; mi < 4; ++mi) {
        float v0 = acc3[mi][0][0], v1 = acc3[mi][0][1], v2 = acc3[mi][0][2], v3 = acc3[mi][0][3];
#pragma unroll
        for (int nt = 1; nt < 4; ++nt) {
            v0 = fmaxf(v0, acc3[mi][nt][0]);
            v1 = fmaxf(v1, acc3[mi][nt][1]);
            v2 = fmaxf(v2, acc3[mi][nt][2]);
            v3 = fmaxf(v3, acc3[mi][nt][3]);
        }
#pragma unroll
        for (int mk = 1; mk < 16; mk <<= 1) {
            v0 = fmaxf(v0, __shfl_xor(v0, mk));
            v1 = fmaxf(v1, __shfl_xor(v1, mk));
            v2 = fmaxf(v2, __shfl_xor(v2, mk));
            v3 = fmaxf(v3, __shfl_xor(v3, mk));
        }
        if (lr == 0) {
            int ch0 = (wv*4 + mi)*16 + lk*4;
            out[((size_t)b*256 + ch0    )*256 + m] = fmaxf(v0 + b22[ch0],     0.f);
            out[((size_t)b*256 + ch0 + 1)*256 + m] = fmaxf(v1 + b22[ch0 + 1], 0.f);
            out[((size_t)b*256 + ch0 + 2)*256 + m] = fmaxf(v2 + b22[ch0 + 2], 0.f);
            out[((size_t)b*256 + ch0 + 3)*256 + m] = fmaxf(v3 + b22[ch0 + 3], 0.f);
        }
    }
}

// ---------------- launch ----------------
extern "C" void kernel_launch(void* const* d_in, const int* in_sizes, int n_in,
                              void* d_out, int out_size, void* d_ws, size_t ws_size,
                              hipStream_t stream)
{
    const float* pts = (const float*)d_in[0];
    const float* w10 = (const float*)d_in[1];
    const float* g10 = (const float*)d_in[2];
    const float* b10 = (const float*)d_in[3];
    const float* w11 = (const float*)d_in[4];
    const float* g11 = (const float*)d_in[5];
    const float* b11 = (const float*)d_in[6];
    const float* w12 = (const float*)d_in[7];
    const float* g12 = (const float*)d_in[8];
    const float* b12 = (const float*)d_in[9];
    const float* w20 = (const float*)d_in[10];
    const float* g20 = (const float*)d_in[11];
    const float* b20 = (const float*)d_in[12];
    const float* w21 = (const float*)d_in[13];
    const float* g21 = (const float*)d_in[14];
    const float* b21 = (const float*)d_in[15];
    const float* w22 = (const float*)d_in[16];
    const float* g22 = (const float*)d_in[17];
    const float* b22 = (const float*)d_in[18];

    float* out = (float*)d_out;
    char* ws = (char*)d_ws;
    int* gidx1 = (int*)(ws + WS_GIDX1);
    int* gidx2 = (int*)(ws + WS_GIDX2);
    _Float16* W1h  = (_Float16*)(ws + WS_W1H);
    _Float16* W2h  = (_Float16*)(ws + WS_W2H);
    _Float16* W3h  = (_Float16*)(ws + WS_W3H);
    _Float16* W1mh = (_Float16*)(ws + WS_W1MH);
    _Float16* W2mh = (_Float16*)(ws + WS_W2MH);
    _Float16* W3mh = (_Float16*)(ws + WS_W3MH);
    float4* pts4 = (float4*)(ws + WS_PTS4);
    float4* p14  = (float4*)(ws + WS_P14);

    float* p1 = out + O_P1;   // [16,3,1024]
    float* f1 = out + O_F1;   // [16,128,1024]
    float* p2 = out + O_P2;   // [16,3,256]
    float* f2 = out + O_F2;   // [16,256,256]

    // K1: fps1 || prep fp16 weights || pack pts4
    fused1<<<16 + 328 + 64, 256, 0, stream>>>(pts, p1, pts4,
                                              w10, g10, w11, g11, w12, g12,
                                              w20, g20, w21, g21, w22, g22,
                                              W1h, W2h, W3h, W1mh, W2mh, W3mh);
    // K2: fps2 (packs p14) || knn1
    fused2<<<16 + NB * 1024, 256, 0, stream>>>(pts4, p1, p2, gidx1, p14);
    // K3: mlp1 (fp16 MFMA) || knn2
    fused3<<<2048 + NB * 256, 256, 0, stream>>>(pts4, p1, gidx1,
                                                W1mh, W2mh, W3mh, b10, b11, b12, f1,
                                                p14, p2, gidx2);
    // K4: mlp2 (fp16 MFMA)
    mlp2_kernel<<<NB * 256, 256, 0, stream>>>(p1, f1, p2, gidx2,
                                              W1h, W2h, W3h, b20, b21, b22, f2);
}

// Round 17
// 1123.781 us; speedup vs baseline: 1.0645x; 1.0645x over previous
//
#include <hip/hip_runtime.h>
#include <math.h>

// ---------------- problem constants ----------------
#define NB   16

// d_out float offsets
#define O_P1 0
#define O_F1 (16*3*1024)            // 49152
#define O_P2 (O_F1 + 16*128*1024)   // 2146304
#define O_F2 (O_P2 + 16*3*256)      // 2158592

// workspace byte offsets
#define WS_GIDX1 0
#define WS_GIDX2 (WS_GIDX1 + 16*1024*32*4)
#define WS_W1H   (WS_GIDX2 + 16*256*64*4)     // fp16 [128][160]  (mlp2 L1)
#define WS_W2H   (WS_W1H  + 128*160*2)        // fp16 [128][128]
#define WS_W3H   (WS_W2H  + 128*128*2)        // fp16 [256][128]
#define WS_W1MH  (WS_W3H  + 256*128*2)        // fp16 [64][32]    (mlp1 L1, K pad 32)
#define WS_W2MH  (WS_W1MH + 64*32*2)          // fp16 [64][64]
#define WS_W3MH  (WS_W2MH + 64*64*2)          // fp16 [128][64]
#define WS_PTS4  (WS_W3MH + 128*64*2)         // float4[16][4096] (x,y,z,|p|^2)
#define WS_P14   (WS_PTS4 + 16*4096*16)       // float4[16][1024] packed p1

#define DEVINL __device__ __forceinline__
typedef unsigned long long u64;
typedef _Float16 f16x8 __attribute__((ext_vector_type(8)));
typedef float f32x4 __attribute__((ext_vector_type(4)));

// order-preserving float -> uint mapping (monotone increasing)
DEVINL unsigned fkey(float f) {
    unsigned u = __float_as_uint(f);
    return (u & 0x80000000u) ? ~u : (u | 0x80000000u);
}

DEVINL u64 shflx64(u64 v, int m) {
    unsigned lo = __shfl_xor((unsigned)v, m);
    unsigned hi = __shfl_xor((unsigned)(v >> 32), m);
    return ((u64)hi << 32) | lo;
}

// inclusive add-scan within wave64 (bcast15 -> rows 1&3, bcast31 -> rows 2&3)
template<int CTRL, int RMASK>
DEVINL unsigned dpp_addstep(unsigned v) {
    unsigned t = (unsigned)__builtin_amdgcn_update_dpp(0, (int)v, CTRL, RMASK, 0xF, true);
    return v + t;
}
DEVINL unsigned wave_scan_add(unsigned v) {
    v = dpp_addstep<0x111, 0xF>(v);
    v = dpp_addstep<0x112, 0xF>(v);
    v = dpp_addstep<0x114, 0xF>(v);
    v = dpp_addstep<0x118, 0xF>(v);
    v = dpp_addstep<0x142, 0xA>(v);
    v = dpp_addstep<0x143, 0xC>(v);
    return v;
}

// XOR-swizzled half-index helpers (16B chunks) — SAME function for write & read.
DEVINL int swz32(int n, int h) {   // row stride 32 halves (64B), 4 chunks
    return n*32 + (((h >> 3) ^ (n & 3)) << 3) + (h & 7);
}
DEVINL int swz64(int n, int h) {   // row stride 64 halves (128B), 8 chunks
    return n*64 + (((h >> 3) ^ (n & 7)) << 3) + (h & 7);
}

// ---------------- shared-memory layouts ----------------
template<int N, int NP> struct __align__(16) FpsS {      // 4-wave FPS
    float4 spts[N];
    int sel[NP];
    u64 rbuf[2][4];
};
struct __align__(16) KnnS {                              // keyless: ~16.4KB -> 8 blk/CU
    unsigned hist[2048];
    unsigned ckey[1024];
    int      cidx[1024];
    unsigned wpart[4];
    unsigned sbin, sKb, scnt, cntL;
};

// ---------------- weight prep: all fp16, gamma-folded ----------------
DEVINL void prep_impl(int e0,
    const float* __restrict__ w10, const float* __restrict__ g10,
    const float* __restrict__ w11, const float* __restrict__ g11,
    const float* __restrict__ w12, const float* __restrict__ g12,
    const float* __restrict__ w20, const float* __restrict__ g20,
    const float* __restrict__ w21, const float* __restrict__ g21,
    const float* __restrict__ w22, const float* __restrict__ g22,
    _Float16* __restrict__ W1h, _Float16* __restrict__ W2h, _Float16* __restrict__ W3h,
    _Float16* __restrict__ W1mh, _Float16* __restrict__ W2mh, _Float16* __restrict__ W3mh)
{
    if (e0 < 20480){ int o = e0/160, i = e0%160;
                     float v = (i < 131) ? w20[o*131 + i]*g20[o] : 0.f;
                     W1h[e0] = (_Float16)v; return; }
    e0 -= 20480;
    if (e0 < 16384){ W2h[e0] = (_Float16)(w21[e0]*g21[e0/128]); return; }
    e0 -= 16384;
    if (e0 < 32768){ W3h[e0] = (_Float16)(w22[e0]*g22[e0/128]); return; }
    e0 -= 32768;
    if (e0 < 2048) { int o = e0>>5, i = e0&31;
                     float v = (i < 6) ? w10[o*6 + i]*g10[o] : 0.f;
                     W1mh[e0] = (_Float16)v; return; }
    e0 -= 2048;
    if (e0 < 4096) { W2mh[e0] = (_Float16)(w11[e0]*g11[e0>>6]); return; }
    e0 -= 4096;
    if (e0 < 8192) { W3mh[e0] = (_Float16)(w12[e0]*g12[e0>>6]); return; }
}

// ---------------- FPS 4-wave (R8 structure; exact jnp semantics) ----------------
template<int N, int NP>
DEVINL void fps_impl(FpsS<N, NP>& sm, const float* __restrict__ pts,
                     float* __restrict__ prop, int b, float4* pack_out)
{
    constexpr int NT = 256;
    constexpr int PT = N / NT;
    int tid = threadIdx.x;
    const float* p = pts + (size_t)b * 3 * N;
    for (int n = tid; n < N; n += NT) {
        float x = p[n], y = p[N+n], z = p[2*N+n];
        sm.spts[n] = make_float4(x, y, z, 0.f);
        if (pack_out) {
            float s = __fadd_rn(__fadd_rn(__fmul_rn(x,x), __fmul_rn(y,y)), __fmul_rn(z,z));
            pack_out[(size_t)b*N + n] = make_float4(x, y, z, s);
        }
    }
    __syncthreads();

    float lx[PT], ly[PT], lz[PT], ld[PT];
    int base = tid * PT;
#pragma unroll
    for (int j = 0; j < PT; ++j) {
        float4 q = sm.spts[base+j];
        lx[j] = q.x; ly[j] = q.y; lz[j] = q.z;
        ld[j] = __builtin_inff();
    }
    if (tid == 0) sm.sel[0] = 0;
    float4 qp = sm.spts[0];
    for (int s = 1; s < NP; ++s) {
        float qx = qp.x, qy = qp.y, qz = qp.z;
        float bd = -1.0f; int bi = 0x7FFFFFFF;
#pragma unroll
        for (int j = 0; j < PT; ++j) {
            float dx = __fsub_rn(lx[j], qx);
            float dy = __fsub_rn(ly[j], qy);
            float dz = __fsub_rn(lz[j], qz);
            float dd = __fadd_rn(__fadd_rn(__fmul_rn(dx,dx), __fmul_rn(dy,dy)), __fmul_rn(dz,dz));
            float v = fminf(ld[j], dd);
            ld[j] = v;
            if (v > bd) { bd = v; bi = base + j; }   // ascending j -> lowest idx on tie
        }
        u64 pk = ((u64)__float_as_uint(bd) << 32) | (unsigned)(~bi);
#pragma unroll
        for (int mk = 1; mk < 64; mk <<= 1) {
            u64 o = shflx64(pk, mk);
            if (o > pk) pk = o;
        }
        if ((tid & 63) == 0) sm.rbuf[s & 1][tid >> 6] = pk;
        __syncthreads();
        u64 g = sm.rbuf[s & 1][0];
#pragma unroll
        for (int w = 1; w < 4; ++w) { u64 o = sm.rbuf[s & 1][w]; if (o > g) g = o; }
        int last = (int)(~(unsigned)g);
        qp = sm.spts[last];
        if (tid == 0) sm.sel[s] = last;
    }
    __syncthreads();
    for (int m = tid; m < NP; m += NT) {
        float4 q = sm.spts[sm.sel[m]];
        prop[(size_t)b*3*NP + m]        = q.x;
        prop[(size_t)b*3*NP + NP + m]   = q.y;
        prop[(size_t)b*3*NP + 2*NP + m] = q.z;
    }
}

// ---------------- KNN keyless (packed points): 11-bit histogram select ----------
template<int N, int K, int M>
DEVINL void knn_impl(KnnS& sm, const float4* __restrict__ pts4,
                     const float* __restrict__ qry, int* __restrict__ gidx, int bm)
{
    int tid = threadIdx.x, lane = tid & 63, wid = tid >> 6;
    int b = bm / M, m = bm % M;
    const float4* p4 = pts4 + (size_t)b * N;
    float qx = qry[(size_t)b*3*M + m];
    float qy = qry[(size_t)b*3*M + M + m];
    float qz = qry[(size_t)b*3*M + 2*M + m];
    float sqq = __fadd_rn(__fadd_rn(__fmul_rn(qx,qx), __fmul_rn(qy,qy)), __fmul_rn(qz,qz));

    for (int e = tid; e < 2048; e += 256) sm.hist[e] = 0;
    if (tid == 0) { sm.scnt = 0; sm.cntL = 0; sm.sbin = 2047u; sm.sKb = 0; }
    __syncthreads();
    for (int n = tid; n < N; n += 256) {
        float4 pp = p4[n];
        float dot = __fadd_rn(__fadd_rn(__fmul_rn(qx,pp.x), __fmul_rn(qy,pp.y)), __fmul_rn(qz,pp.z));
        float d = __fadd_rn(__fsub_rn(sqq, __fmul_rn(2.0f, dot)), pp.w);
        atomicAdd(&sm.hist[fkey(d) >> 21], 1u);
    }
    __syncthreads();
    unsigned hloc[8], s8 = 0;
#pragma unroll
    for (int j = 0; j < 8; ++j) { hloc[j] = sm.hist[tid*8 + j]; s8 += hloc[j]; }
    unsigned sc = wave_scan_add(s8);
    if (lane == 63) sm.wpart[wid] = sc;
    __syncthreads();
    unsigned woff = 0;
    for (int w = 0; w < wid; ++w) woff += sm.wpart[w];
    unsigned cumEnd = sc + woff;
    unsigned cbase = cumEnd - s8;
    if ((unsigned)K > cbase && (unsigned)K <= cumEnd) {
        unsigned run = cbase;
#pragma unroll
        for (int j = 0; j < 8; ++j) {
            if ((unsigned)K > run && (unsigned)K <= run + hloc[j]) { sm.sbin = (unsigned)(tid*8 + j); sm.sKb = run; }
            run += hloc[j];
        }
    }
    __syncthreads();
    unsigned bin1 = sm.sbin;
    unsigned Kb   = sm.sKb;
    int* gout = gidx + ((size_t)b * M + m) * K;
    for (int n = tid; n < N; n += 256) {
        float4 pp = p4[n];
        float dot = __fadd_rn(__fadd_rn(__fmul_rn(qx,pp.x), __fmul_rn(qy,pp.y)), __fmul_rn(qz,pp.z));
        float d = __fadd_rn(__fsub_rn(sqq, __fmul_rn(2.0f, dot)), pp.w);
        unsigned k = fkey(d), pfx = k >> 21;
        if (pfx < bin1) {
            unsigned pos = atomicAdd(&sm.cntL, 1u);
            if (pos < (unsigned)K) gout[pos] = n;
        } else if (pfx == bin1) {
            unsigned pos = atomicAdd(&sm.scnt, 1u);
            if (pos < 1024u) { sm.ckey[pos] = k; sm.cidx[pos] = n; }
        }
    }
    __syncthreads();
    int cnt = (int)sm.scnt; if (cnt > 1024) cnt = 1024;
    int need = K - (int)Kb;
    if (tid < 64) {
        for (int c = lane; c < cnt; c += 64) {
            unsigned mk = sm.ckey[c]; int mi = sm.cidx[c];
            int rank = 0;
            for (int l = 0; l < cnt; ++l) {
                unsigned ok = sm.ckey[l];
                rank += (ok < mk || (ok == mk && sm.cidx[l] < mi)) ? 1 : 0;
            }
            if (rank < need && (int)Kb + rank < K) gout[Kb + rank] = mi;
        }
    }
}

// ---------------- fused kernels ----------------
// K1: fps1 (0..15) || prep fp16 weights (16..343) || pack pts4 (344..407)
__global__ __launch_bounds__(256) void fused1(
    const float* __restrict__ pts, float* __restrict__ p1, float4* __restrict__ pts4,
    const float* w10, const float* g10, const float* w11, const float* g11,
    const float* w12, const float* g12, const float* w20, const float* g20,
    const float* w21, const float* g21, const float* w22, const float* g22,
    _Float16* W1h, _Float16* W2h, _Float16* W3h,
    _Float16* W1mh, _Float16* W2mh, _Float16* W3mh)
{
    __shared__ FpsS<4096, 1024> sm;
    if (blockIdx.x < 16) {
        fps_impl<4096, 1024>(sm, pts, p1, blockIdx.x, nullptr);
    } else if (blockIdx.x < 344) {
        prep_impl((blockIdx.x - 16) * 256 + threadIdx.x,
                  w10, g10, w11, g11, w12, g12, w20, g20, w21, g21, w22, g22,
                  W1h, W2h, W3h, W1mh, W2mh, W3mh);
    } else {
        int pblk = blockIdx.x - 344;   // 0..63, 1024 points each
#pragma unroll
        for (int i = 0; i < 4; ++i) {
            int idx = pblk * 1024 + i * 256 + threadIdx.x;
            int b = idx >> 12, n = idx & 4095;
            const float* p = pts + (size_t)b * 3 * 4096;
            float x = p[n], y = p[4096 + n], z = p[2*4096 + n];
            float s = __fadd_rn(__fadd_rn(__fmul_rn(x,x), __fmul_rn(y,y)), __fmul_rn(z,z));
            pts4[idx] = make_float4(x, y, z, s);
        }
    }
}

// K2: fps2 4-wave (0..15, packs p14) || knn1 (16..16399)
union SmemK2 { FpsS<1024, 256> fps; KnnS knn; };
__global__ __launch_bounds__(256) void fused2(
    const float4* __restrict__ pts4, const float* __restrict__ p1,
    float* __restrict__ p2, int* __restrict__ gidx1, float4* __restrict__ p14)
{
    __shared__ SmemK2 sm;
    if (blockIdx.x < 16) {
        fps_impl<1024, 256>(sm.fps, p1, p2, blockIdx.x, p14);
    } else {
        knn_impl<4096, 32, 1024>(sm.knn, pts4, p1, gidx1, blockIdx.x - 16);
    }
}

// ---------------- K3: mlp1 via fp16 MFMA ----------------
// One block per 8 positions; wave-local h rows -> no barriers in GEMM chain.
__global__ __launch_bounds__(256) void mlp1_mfma(
    const float4* __restrict__ pts4,  // [B][4096] packed
    const float* __restrict__ q,      // points1 [B,3,1024]
    const int*   __restrict__ gidx,   // [B,1024,32]
    const _Float16* __restrict__ W1mh, // [64][32]
    const _Float16* __restrict__ W2mh, // [64][64]
    const _Float16* __restrict__ W3mh, // [128][64]
    const float* __restrict__ b1, const float* __restrict__ b2, const float* __restrict__ b3,
    float* __restrict__ out)          // feats1 [B,128,1024]
{
    __shared__ _Float16 xT [256*32];   // swizzled, stride 32
    __shared__ _Float16 h1T[256*64];   // swizzled, stride 64 (h1 -> h2 in place)
    __shared__ float sout[128*8];
    __shared__ int   sgi[256];
    __shared__ float sq[24];           // [c][pos]

    int tid = threadIdx.x;
    int pid0 = blockIdx.x * 8;
    int b = pid0 >> 10, m0 = pid0 & 1023;

    sgi[tid] = gidx[((size_t)b*1024 + m0)*32 + tid];
    if (tid < 24) {
        int c = tid >> 3, j = tid & 7;
        sq[tid] = q[((size_t)b*3 + c)*1024 + m0 + j];
    }
    __syncthreads();

    union Pk4 { _Float16 h[4]; u64 u; };
    {
        int n = tid, pos = n >> 5;
        float4 pp = pts4[(size_t)b*4096 + sgi[n]];
        float v[8];
        v[0] = pp.x - sq[pos]; v[1] = pp.y - sq[8+pos]; v[2] = pp.z - sq[16+pos];
        v[3] = pp.x; v[4] = pp.y; v[5] = pp.z; v[6] = 0.f; v[7] = 0.f;
#pragma unroll
        for (int qi = 0; qi < 8; ++qi) {
            Pk4 pk;
            if (qi < 2) {
#pragma unroll
                for (int j = 0; j < 4; ++j) pk.h[j] = (_Float16)v[qi*4 + j];
            } else pk.u = 0;
            *(u64*)&xT[swz32(n, qi*4)] = pk.u;
        }
    }
    __syncthreads();

    int wv = tid >> 6, l = tid & 63;
    int lr = l & 15, lk = l >> 4;

    // GEMM1: H1[64][256] = W1[64][32] * X[32][256]
    f32x4 acc[4][4];
#pragma unroll
    for (int mi = 0; mi < 4; ++mi)
#pragma unroll
        for (int nt = 0; nt < 4; ++nt) acc[mi][nt] = (f32x4){0.f,0.f,0.f,0.f};
    {
        int kk = lk*8;
        f16x8 bf[4];
#pragma unroll
        for (int nt = 0; nt < 4; ++nt)
            bf[nt] = *(const f16x8*)&xT[swz32((4*wv + nt)*16 + lr, kk)];
#pragma unroll
        for (int mi = 0; mi < 4; ++mi) {
            f16x8 af = *(const f16x8*)&W1mh[(mi*16 + lr)*32 + kk];
#pragma unroll
            for (int nt = 0; nt < 4; ++nt)
                acc[mi][nt] = __builtin_amdgcn_mfma_f32_16x16x32_f16(af, bf[nt], acc[mi][nt], 0, 0, 0);
        }
    }
#pragma unroll
    for (int mi = 0; mi < 4; ++mi) {
        int ch0 = mi*16 + lk*4;
        float bb0 = b1[ch0], bb1 = b1[ch0+1], bb2 = b1[ch0+2], bb3 = b1[ch0+3];
#pragma unroll
        for (int nt = 0; nt < 4; ++nt) {
            int n = (4*wv + nt)*16 + lr;
            Pk4 pk;
            pk.h[0] = (_Float16)fmaxf(acc[mi][nt][0] + bb0, 0.f);
            pk.h[1] = (_Float16)fmaxf(acc[mi][nt][1] + bb1, 0.f);
            pk.h[2] = (_Float16)fmaxf(acc[mi][nt][2] + bb2, 0.f);
            pk.h[3] = (_Float16)fmaxf(acc[mi][nt][3] + bb3, 0.f);
            *(u64*)&h1T[swz64(n, ch0)] = pk.u;
        }
    }

    // GEMM2: H2 = W2 * H1 (wave-local rows; in-place)
#pragma unroll
    for (int mi = 0; mi < 4; ++mi)
#pragma unroll
        for (int nt = 0; nt < 4; ++nt) acc[mi][nt] = (f32x4){0.f,0.f,0.f,0.f};
#pragma unroll
    for (int ks = 0; ks < 2; ++ks) {
        int kk = ks*32 + lk*8;
        f16x8 bf[4];
#pragma unroll
        for (int nt = 0; nt < 4; ++nt)
            bf[nt] = *(const f16x8*)&h1T[swz64((4*wv + nt)*16 + lr, kk)];
#pragma unroll
        for (int mi = 0; mi < 4; ++mi) {
            f16x8 af = *(const f16x8*)&W2mh[(mi*16 + lr)*64 + kk];
#pragma unroll
            for (int nt = 0; nt < 4; ++nt)
                acc[mi][nt] = __builtin_amdgcn_mfma_f32_16x16x32_f16(af, bf[nt], acc[mi][nt], 0, 0, 0);
        }
    }
#pragma unroll
    for (int mi = 0; mi < 4; ++mi) {
        int ch0 = mi*16 + lk*4;
        float bb0 = b2[ch0], bb1 = b2[ch0+1], bb2 = b2[ch0+2], bb3 = b2[ch0+3];
#pragma unroll
        for (int nt = 0; nt < 4; ++nt) {
            int n = (4*wv + nt)*16 + lr;
            Pk4 pk;
            pk.h[0] = (_Float16)fmaxf(acc[mi][nt][0] + bb0, 0.f);
            pk.h[1] = (_Float16)fmaxf(acc[mi][nt][1] + bb1, 0.f);
            pk.h[2] = (_Float16)fmaxf(acc[mi][nt][2] + bb2, 0.f);
            pk.h[3] = (_Float16)fmaxf(acc[mi][nt][3] + bb3, 0.f);
            *(u64*)&h1T[swz64(n, ch0)] = pk.u;
        }
    }

    // GEMM3: Y[128][256] = W3[128][64] * H2 + maxpool(32)
    f32x4 acc3[8][4];
#pragma unroll
    for (int mi = 0; mi < 8; ++mi)
#pragma unroll
        for (int nt = 0; nt < 4; ++nt) acc3[mi][nt] = (f32x4){0.f,0.f,0.f,0.f};
#pragma unroll
    for (int ks = 0; ks < 2; ++ks) {
        int kk = ks*32 + lk*8;
        f16x8 bf[4];
#pragma unroll
        for (int nt = 0; nt < 4; ++nt)
            bf[nt] = *(const f16x8*)&h1T[swz64((4*wv + nt)*16 + lr, kk)];
#pragma unroll
        for (int mi = 0; mi < 8; ++mi) {
            f16x8 af = *(const f16x8*)&W3mh[(mi*16 + lr)*64 + kk];
#pragma unroll
            for (int nt = 0; nt < 4; ++nt)
                acc3[mi][nt] = __builtin_amdgcn_mfma_f32_16x16x32_f16(af, bf[nt], acc3[mi][nt], 0, 0, 0);
        }
    }
#pragma unroll
    for (int mi = 0; mi < 8; ++mi) {
        float va[4], vb[4];
#pragma unroll
        for (int r = 0; r < 4; ++r) {
            va[r] = fmaxf(acc3[mi][0][r], acc3[mi][1][r]);
            vb[r] = fmaxf(acc3[mi][2][r], acc3[mi][3][r]);
        }
#pragma unroll
        for (int mk = 1; mk < 16; mk <<= 1) {
#pragma unroll
            for (int r = 0; r < 4; ++r) {
                va[r] = fmaxf(va[r], __shfl_xor(va[r], mk));
                vb[r] = fmaxf(vb[r], __shfl_xor(vb[r], mk));
            }
        }
        if (lr == 0) {
            int ch0 = mi*16 + lk*4;
#pragma unroll
            for (int r = 0; r < 4; ++r) {
                float bias = b3[ch0 + r];
                sout[(ch0 + r)*8 + 2*wv    ] = fmaxf(va[r] + bias, 0.f);
                sout[(ch0 + r)*8 + 2*wv + 1] = fmaxf(vb[r] + bias, 0.f);
            }
        }
    }
    __syncthreads();
    for (int e = tid; e < 128*8; e += 256) {
        int cc = e >> 3, j = e & 7;
        out[((size_t)b*128 + cc)*1024 + m0 + j] = sout[e];
    }
}

// ---------------- K4: knn2 standalone (16.4KB LDS -> 8 blocks/CU) ----------------
__global__ __launch_bounds__(256) void knn2_kernel(
    const float4* __restrict__ p14, const float* __restrict__ p2, int* __restrict__ gidx2)
{
    __shared__ KnnS sm;
    knn_impl<1024, 64, 256>(sm, p14, p2, gidx2, blockIdx.x);
}

// ---------------- K5: mlp2 via fp16 MFMA (R14, verified) ----------------
__global__ __launch_bounds__(256) void mlp2_kernel(
    const float* __restrict__ p1,   // [B,3,1024]
    const float* __restrict__ f1,   // [B,128,1024]
    const float* __restrict__ q2,   // [B,3,256]
    const int*   __restrict__ gidx, // [B,256,64]
    const _Float16* __restrict__ W1h,  // [128][160]
    const _Float16* __restrict__ W2h,  // [128][128]
    const _Float16* __restrict__ W3h,  // [256][128]
    const float* __restrict__ b20, const float* __restrict__ b21, const float* __restrict__ b22,
    float* __restrict__ out)        // feats2 [B,256,256]
{
    __shared__ _Float16 xT[64*168];    // X^T (n-major, stride 168); later h2T (stride 136)
    __shared__ _Float16 h1T[64*136];
    __shared__ int   sgi[64];
    __shared__ float sq[3];

    int tid = threadIdx.x;
    int b = blockIdx.x >> 8, m = blockIdx.x & 255;
    if (tid < 64) sgi[tid] = gidx[((size_t)b*256 + m)*64 + tid];
    else if (tid < 67) sq[tid-64] = q2[((size_t)b*3 + (tid-64))*256 + m];
    __syncthreads();

    union Pk4 { _Float16 h[4]; u64 u; };
    for (int e = tid; e < 40*64; e += 256) {
        int qi = e >> 6, n = e & 63;
        int gi = sgi[n];
        Pk4 pk;
#pragma unroll
        for (int j = 0; j < 4; ++j) {
            int i = qi*4 + j;
            float v;
            if (i < 3)        v = p1[((size_t)b*3 + i)*1024 + gi] - sq[i];
            else if (i < 131) v = f1[((size_t)b*128 + (i-3))*1024 + gi];
            else              v = 0.f;
            pk.h[j] = (_Float16)v;
        }
        *(u64*)&xT[n*168 + qi*4] = pk.u;
    }
    __syncthreads();

    int wv = tid >> 6, l = tid & 63;
    int lr = l & 15, lk = l >> 4;

    // GEMM1: Y1[128][64] = W1[128][160] * X[160][64]
    f32x4 acc[2][4];
#pragma unroll
    for (int mi = 0; mi < 2; ++mi)
#pragma unroll
        for (int nt = 0; nt < 4; ++nt) acc[mi][nt] = (f32x4){0.f,0.f,0.f,0.f};
#pragma unroll
    for (int ks = 0; ks < 5; ++ks) {
        int kk = ks*32 + lk*8;
        f16x8 bf[4];
#pragma unroll
        for (int nt = 0; nt < 4; ++nt)
            bf[nt] = *(const f16x8*)&xT[(nt*16 + lr)*168 + kk];
#pragma unroll
        for (int mi = 0; mi < 2; ++mi) {
            f16x8 af = *(const f16x8*)&W1h[(size_t)((wv*2 + mi)*16 + lr)*160 + kk];
#pragma unroll
            for (int nt = 0; nt < 4; ++nt)
                acc[mi][nt] = __builtin_amdgcn_mfma_f32_16x16x32_f16(af, bf[nt], acc[mi][nt], 0, 0, 0);
        }
    }
#pragma unroll
    for (int mi = 0; mi < 2; ++mi) {
        int ch0 = (wv*2 + mi)*16 + lk*4;
        float bb0 = b20[ch0], bb1 = b20[ch0+1], bb2 = b20[ch0+2], bb3 = b20[ch0+3];
#pragma unroll
        for (int nt = 0; nt < 4; ++nt) {
            int n = nt*16 + lr;
            Pk4 pk;
            pk.h[0] = (_Float16)fmaxf(acc[mi][nt][0] + bb0, 0.f);
            pk.h[1] = (_Float16)fmaxf(acc[mi][nt][1] + bb1, 0.f);
            pk.h[2] = (_Float16)fmaxf(acc[mi][nt][2] + bb2, 0.f);
            pk.h[3] = (_Float16)fmaxf(acc[mi][nt][3] + bb3, 0.f);
            *(u64*)&h1T[n*136 + ch0] = pk.u;
        }
    }
    __syncthreads();

    // GEMM2: Y2 = W2 * H1; h2T into xT region
    _Float16* h2T = xT;
#pragma unroll
    for (int mi = 0; mi < 2; ++mi)
#pragma unroll
        for (int nt = 0; nt < 4; ++nt) acc[mi][nt] = (f32x4){0.f,0.f,0.f,0.f};
#pragma unroll
    for (int ks = 0; ks < 4; ++ks) {
        int kk = ks*32 + lk*8;
        f16x8 bf[4];
#pragma unroll
        for (int nt = 0; nt < 4; ++nt)
            bf[nt] = *(const f16x8*)&h1T[(nt*16 + lr)*136 + kk];
#pragma unroll
        for (int mi = 0; mi < 2; ++mi) {
            f16x8 af = *(const f16x8*)&W2h[(size_t)((wv*2 + mi)*16 + lr)*128 + kk];
#pragma unroll
            for (int nt = 0; nt < 4; ++nt)
                acc[mi][nt] = __builtin_amdgcn_mfma_f32_16x16x32_f16(af, bf[nt], acc[mi][nt], 0, 0, 0);
        }
    }
    __syncthreads();
#pragma unroll
    for (int mi = 0; mi < 2; ++mi) {
        int ch0 = (wv*2 + mi)*16 + lk*4;
        float bb0 = b21[ch0], bb1 = b21[ch0+1], bb2 = b21[ch0+2], bb3 = b21[ch0+3];
#pragma unroll
        for (int nt = 0; nt < 4; ++nt) {
            int n = nt*16 + lr;
            Pk4 pk;
            pk.h[0] = (_Float16)fmaxf(acc[mi][nt][0] + bb0, 0.f);
            pk.h[1] = (_Float16)fmaxf(acc[mi][nt][1] + bb1, 0.f);
            pk.h[2] = (_Float16)fmaxf(acc[mi][nt][2] + bb2, 0.f);
            pk.h[3] = (_Float16)fmaxf(acc[mi][nt][3] + bb3, 0.f);
            *(u64*)&h2T[n*136 + ch0] = pk.u;
        }
    }
    __syncthreads();

    // GEMM3: Y3[256][64] = W3 * H2, maxpool over n
    f32x4 acc3[4][4];
#pragma unroll
    for (int mi = 0; mi < 4; ++mi)
#pragma unroll
        for (int nt = 0; nt < 4; ++nt) acc3[mi][nt] = (f32x4){0.f,0.f,0.f,0.f};
#pragma unroll
    for (int ks = 0; ks < 4; ++ks) {
        int kk = ks*32 + lk*8;
        f16x8 bf[4];
#pragma unroll
        for (int nt = 0; nt < 4; ++nt)
            bf[nt] = *(const f16x8*)&h2T[(nt*16 + lr)*136 + kk];
#pragma unroll
        for (int mi = 0; mi < 4; ++mi) {
            f16x8 af = *(const f16x8*)&W3h[(size_t)((wv*4 + mi)*16 + lr)*128 + kk];
#pragma unroll
            for (int nt = 0; nt < 4; ++nt)
                acc3[mi][nt] = __builtin_amdgcn_mfma_f32_16x16x32_f16(af, bf[nt], acc3[mi][nt], 0, 0, 0);
        }
    }
#pragma unroll
    for (int mi = 0; mi < 4; ++mi) {
        float v0 = acc3[mi][0][0], v1 = acc3[mi][0][1], v2 = acc3[mi][0][2], v3 = acc3[mi][0][3];
#pragma unroll
        for (int nt = 1; nt < 4; ++nt) {
            v0 = fmaxf(v0, acc3[mi][nt][0]);
            v1 = fmaxf(v1, acc3[mi][nt][1]);
            v2 = fmaxf(v2, acc3[mi][nt][2]);
            v3 = fmaxf(v3, acc3[mi][nt][3]);
        }
#pragma unroll
        for (int mk = 1; mk < 16; mk <<= 1) {
            v0 = fmaxf(v0, __shfl_xor(v0, mk));
            v1 = fmaxf(v1, __shfl_xor(v1, mk));
            v2 = fmaxf(v2, __shfl_xor(v2, mk));
            v3 = fmaxf(v3, __shfl_xor(v3, mk));
        }
        if (lr == 0) {
            int ch0 = (wv*4 + mi)*16 + lk*4;
            out[((size_t)b*256 + ch0    )*256 + m] = fmaxf(v0 + b22[ch0],     0.f);
            out[((size_t)b*256 + ch0 + 1)*256 + m] = fmaxf(v1 + b22[ch0 + 1], 0.f);
            out[((size_t)b*256 + ch0 + 2)*256 + m] = fmaxf(v2 + b22[ch0 + 2], 0.f);
            out[((size_t)b*256 + ch0 + 3)*256 + m] = fmaxf(v3 + b22[ch0 + 3], 0.f);
        }
    }
}

// ---------------- launch ----------------
extern "C" void kernel_launch(void* const* d_in, const int* in_sizes, int n_in,
                              void* d_out, int out_size, void* d_ws, size_t ws_size,
                              hipStream_t stream)
{
    const float* pts = (const float*)d_in[0];
    const float* w10 = (const float*)d_in[1];
    const float* g10 = (const float*)d_in[2];
    const float* b10 = (const float*)d_in[3];
    const float* w11 = (const float*)d_in[4];
    const float* g11 = (const float*)d_in[5];
    const float* b11 = (const float*)d_in[6];
    const float* w12 = (const float*)d_in[7];
    const float* g12 = (const float*)d_in[8];
    const float* b12 = (const float*)d_in[9];
    const float* w20 = (const float*)d_in[10];
    const float* g20 = (const float*)d_in[11];
    const float* b20 = (const float*)d_in[12];
    const float* w21 = (const float*)d_in[13];
    const float* g21 = (const float*)d_in[14];
    const float* b21 = (const float*)d_in[15];
    const float* w22 = (const float*)d_in[16];
    const float* g22 = (const float*)d_in[17];
    const float* b22 = (const float*)d_in[18];

    float* out = (float*)d_out;
    char* ws = (char*)d_ws;
    int* gidx1 = (int*)(ws + WS_GIDX1);
    int* gidx2 = (int*)(ws + WS_GIDX2);
    _Float16* W1h  = (_Float16*)(ws + WS_W1H);
    _Float16* W2h  = (_Float16*)(ws + WS_W2H);
    _Float16* W3h  = (_Float16*)(ws + WS_W3H);
    _Float16* W1mh = (_Float16*)(ws + WS_W1MH);
    _Float16* W2mh = (_Float16*)(ws + WS_W2MH);
    _Float16* W3mh = (_Float16*)(ws + WS_W3MH);
    float4* pts4 = (float4*)(ws + WS_PTS4);
    float4* p14  = (float4*)(ws + WS_P14);

    float* p1 = out + O_P1;   // [16,3,1024]
    float* f1 = out + O_F1;   // [16,128,1024]
    float* p2 = out + O_P2;   // [16,3,256]
    float* f2 = out + O_F2;   // [16,256,256]

    // K1: fps1 || prep fp16 weights || pack pts4
    fused1<<<16 + 328 + 64, 256, 0, stream>>>(pts, p1, pts4,
                                              w10, g10, w11, g11, w12, g12,
                                              w20, g20, w21, g21, w22, g22,
                                              W1h, W2h, W3h, W1mh, W2mh, W3mh);
    // K2: fps2 (packs p14) || knn1
    fused2<<<16 + NB * 1024, 256, 0, stream>>>(pts4, p1, p2, gidx1, p14);
    // K3: mlp1 (fp16 MFMA)
    mlp1_mfma<<<NB * 128, 256, 0, stream>>>(pts4, p1, gidx1,
                                            W1mh, W2mh, W3mh, b10, b11, b12, f1);
    // K4: knn2
    knn2_kernel<<<NB * 256, 256, 0, stream>>>(p14, p2, gidx2);
    // K5: mlp2 (fp16 MFMA)
    mlp2_kernel<<<NB * 256, 256, 0, stream>>>(p1, f1, p2, gidx2,
                                              W1h, W2h, W3h, b20, b21, b22, f2);
}